// Round 10
// baseline (673.984 us; speedup 1.0000x reference)
//
#include <hip/hip_runtime.h>
#include <hip/hip_bf16.h>

typedef __attribute__((ext_vector_type(4))) float f32x4;
typedef __attribute__((ext_vector_type(8))) _Float16 f16x8;
typedef __attribute__((ext_vector_type(4))) _Float16 f16x4;

#define CHUNK 4096   // edges per pass-1 block
#define BSH 7        // nodes per bucket = 128
#define CAP 4096     // max edges per bucket handled in LDS fast path

// h layout: 4 feature-quarter planes, plane p holds columns [32p,32p+32) of all
// rows contiguously: hp[p*N*32 + r*32 + c]. A plane (3.2 MB) fits each XCD L2.

// ---------------- fp32 -> fp16 convert into planes ----------------
__global__ __launch_bounds__(256) void cvt_kernel(const float* __restrict__ x,
                                                  _Float16* __restrict__ hp, int N) {
  int i = blockIdx.x * blockDim.x + threadIdx.x;  // over N*32 quads of 4 elems
  if (i < N * 32) {
    int r = i >> 5, jg = i & 31;
    float4 v = *(const float4*)(x + (size_t)r * 128 + jg * 4);
    f16x4 o = {(_Float16)v.x, (_Float16)v.y, (_Float16)v.z, (_Float16)v.w};
    int plane = jg >> 3, wc = (jg & 7) * 4;
    *(f16x4*)(hp + (size_t)plane * N * 32 + (size_t)r * 32 + wc) = o;
  }
}

// ---------------- CSR build: bucketed counting sort ----------------
__global__ __launch_bounds__(256) void bhist_kernel(const int* __restrict__ dst,
                                                    int* __restrict__ blkhist, int E, int nb) {
  __shared__ int l[512];
  int t = threadIdx.x;
  for (int i = t; i < 512; i += 256) l[i] = 0;
  __syncthreads();
  int cbase = blockIdx.x * CHUNK;
  #pragma unroll
  for (int i = 0; i < CHUNK / 256; ++i) {
    int idx = cbase + i * 256 + t;
    if (idx < E) atomicAdd(&l[dst[idx] >> BSH], 1);
  }
  __syncthreads();
  for (int i = t; i < 512; i += 256) blkhist[blockIdx.x * 512 + i] = l[i];
}

__global__ __launch_bounds__(512) void bscan_kernel(const int* __restrict__ blkhist, int nblk,
                                                    int* __restrict__ base,
                                                    int* __restrict__ gcursor, int nb, int E) {
  __shared__ int wsum[8], wpre[8];
  int t = threadIdx.x, lane = t & 63, w = t >> 6;
  int v = 0;
  int b = 0;
  for (; b + 4 <= nblk; b += 4)
    v += blkhist[b * 512 + t] + blkhist[(b + 1) * 512 + t] +
         blkhist[(b + 2) * 512 + t] + blkhist[(b + 3) * 512 + t];
  for (; b < nblk; ++b) v += blkhist[b * 512 + t];
  int incl = v;
  #pragma unroll
  for (int o = 1; o < 64; o <<= 1) {
    int x = __shfl_up(incl, o, 64);
    if (lane >= o) incl += x;
  }
  if (lane == 63) wsum[w] = incl;
  __syncthreads();
  if (t == 0) {
    int run = 0;
    #pragma unroll
    for (int q = 0; q < 8; ++q) { wpre[q] = run; run += wsum[q]; }
  }
  __syncthreads();
  int excl = wpre[w] + incl - v;
  if (t < nb) { base[t] = excl; gcursor[t] = excl; }
  if (t == 0) base[nb] = E;
}

__global__ __launch_bounds__(256) void bscatter_kernel(const int* __restrict__ src,
                                                       const int* __restrict__ dst,
                                                       int* __restrict__ gcursor,
                                                       int2* __restrict__ pairs, int E, int nb) {
  __shared__ int lcnt[512], lstart[512], lpos[512], lgbase[512];
  __shared__ int2 lp[CHUNK];
  __shared__ int wsum[4], wpre[4];
  int t = threadIdx.x, lane = t & 63, w = t >> 6;
  for (int i = t; i < 512; i += 256) lcnt[i] = 0;
  __syncthreads();
  int cbase = blockIdx.x * CHUNK;
  int m = E - cbase; if (m > CHUNK) m = CHUNK;
  #pragma unroll
  for (int i = 0; i < CHUNK / 256; ++i) {
    int idx = i * 256 + t;
    if (idx < m) atomicAdd(&lcnt[dst[cbase + idx] >> BSH], 1);
  }
  __syncthreads();
  int c0 = lcnt[2 * t], c1 = lcnt[2 * t + 1];
  int s = c0 + c1, incl = s;
  #pragma unroll
  for (int o = 1; o < 64; o <<= 1) {
    int x = __shfl_up(incl, o, 64);
    if (lane >= o) incl += x;
  }
  if (lane == 63) wsum[w] = incl;
  __syncthreads();
  if (t == 0) {
    int run = 0;
    #pragma unroll
    for (int q = 0; q < 4; ++q) { wpre[q] = run; run += wsum[q]; }
  }
  __syncthreads();
  int excl = wpre[w] + incl - s;
  lstart[2 * t] = excl;          lpos[2 * t] = excl;
  lstart[2 * t + 1] = excl + c0; lpos[2 * t + 1] = excl + c0;
  if (2 * t < nb && c0 > 0) lgbase[2 * t] = atomicAdd(&gcursor[2 * t], c0);
  if (2 * t + 1 < nb && c1 > 0) lgbase[2 * t + 1] = atomicAdd(&gcursor[2 * t + 1], c1);
  __syncthreads();
  #pragma unroll
  for (int i = 0; i < CHUNK / 256; ++i) {
    int idx = i * 256 + t;
    if (idx < m) {
      int d = dst[cbase + idx], sv = src[cbase + idx];
      int p = atomicAdd(&lpos[d >> BSH], 1);
      lp[p] = make_int2(sv, d);
    }
  }
  __syncthreads();
  for (int i = t; i < m; i += 256) {
    int2 pr = lp[i];
    int b = pr.y >> BSH;
    pairs[lgbase[b] + (i - lstart[b])] = pr;
  }
}

// Pass 2: per-bucket local CSR; also histogram node degrees into dcnt[64]
__global__ __launch_bounds__(256) void bbuild_kernel(const int2* __restrict__ pairs,
                                                     const int* __restrict__ base,
                                                     int* __restrict__ row_ptr,
                                                     int* __restrict__ col,
                                                     int* __restrict__ dcnt, int N, int E) {
  __shared__ int cnt[128], cur[128], w2[2];
  __shared__ int cl[CAP];
  int b = blockIdx.x, t = threadIdx.x;
  int mb = base[b], me = base[b + 1], m = me - mb;
  if (t < 128) cnt[t] = 0;
  __syncthreads();
  for (int i = t; i < m; i += 256) atomicAdd(&cnt[pairs[mb + i].y & 127], 1);
  __syncthreads();
  int v = 0, incl = 0;
  if (t < 128) {
    v = cnt[t]; incl = v;
    #pragma unroll
    for (int o = 1; o < 64; o <<= 1) {
      int x = __shfl_up(incl, o, 64);
      if ((t & 63) >= o) incl += x;
    }
    if ((t & 63) == 63) w2[t >> 6] = incl;
  }
  __syncthreads();
  if (t < 128) {
    int excl = incl - v + ((t & 64) ? w2[0] : 0);
    cur[t] = excl;
    int node = (b << BSH) + t;
    if (node < N) {
      row_ptr[node] = mb + excl;
      atomicAdd(&dcnt[v < 63 ? v : 63], 1);  // degree histogram
    }
  }
  if (b == 0 && t == 0) row_ptr[N] = E;
  __syncthreads();
  if (m <= CAP) {
    for (int i = t; i < m; i += 256) {
      int2 p = pairs[mb + i];
      int pos = atomicAdd(&cur[p.y & 127], 1);
      cl[pos] = p.x;
    }
    __syncthreads();
    for (int i = t; i < m; i += 256) col[mb + i] = cl[i];
  } else {
    for (int i = t; i < m; i += 256) {
      int2 p = pairs[mb + i];
      int pos = atomicAdd(&cur[p.y & 127], 1);
      col[mb + pos] = p.x;
    }
  }
}

// ---------------- degree-sort: scan 64 bins, scatter rows by degree rank ----------------
__global__ void dscan_kernel(const int* __restrict__ dcnt, int* __restrict__ dcur) {
  int t = threadIdx.x;  // 64 threads
  int v = dcnt[t];
  int incl = v;
  #pragma unroll
  for (int o = 1; o < 64; o <<= 1) {
    int x = __shfl_up(incl, o, 64);
    if (t >= o) incl += x;
  }
  dcur[t] = incl - v;  // exclusive
}

__global__ __launch_bounds__(256) void dscatter_kernel(const int* __restrict__ row_ptr,
                                                       int* __restrict__ dcur,
                                                       int* __restrict__ perm,
                                                       int2* __restrict__ prange, int N) {
  int r = blockIdx.x * 256 + threadIdx.x;
  if (r < N) {
    int s = row_ptr[r], e = row_ptr[r + 1];
    int deg = e - s;
    int b = deg < 63 ? deg : 63;
    int pos = atomicAdd(&dcur[b], 1);
    perm[pos] = r;
    prange[pos] = make_int2(s, e);
  }
}

// ---------------- weight prep: all 5 layers in one launch ----------------
struct W10 { const float* p[10]; };  // p[0..4]=Wrel, p[5..9]=Wroot

__global__ __launch_bounds__(256) void prep_kernel(W10 wp, _Float16* __restrict__ Whi,
                                                   _Float16* __restrict__ Wlo, float wscale) {
  int l = blockIdx.x >> 7;
  int idx = (blockIdx.x & 127) * 256 + threadIdx.x;  // col*256 + k
  int col = idx >> 8;
  int k = idx & 255;
  const float* __restrict__ Wrel = wp.p[l];
  const float* __restrict__ Wroot = wp.p[5 + l];
  float v = (k < 128) ? Wrel[k * 128 + col] : Wroot[(k - 128) * 128 + col];
  v *= wscale;
  _Float16 hi = (_Float16)v;
  _Float16 lo = (_Float16)(v - (float)hi);
  Whi[(size_t)l * 32768 + idx] = hi;
  Wlo[(size_t)l * 32768 + idx] = lo;
}

// ---------------- SpMM over feature-quarter planes, degree-sorted rows ----------------
// pass p: gather 64B/edge from plane p (3.2 MB, L2-resident per XCD).
// 4-lane quads own one (degree-rank-ordered) row; 8-deep col-prefetched pipeline.
__global__ __launch_bounds__(256) void spmm_kernel(const _Float16* __restrict__ hplanes,
                                                   const int* __restrict__ perm,
                                                   const int2* __restrict__ prange,
                                                   const int* __restrict__ col,
                                                   _Float16* __restrict__ aggplanes,
                                                   int N, int nbpp) {
  int pass = blockIdx.x / nbpp;
  int blk = blockIdx.x - pass * nbpp;
  int t = threadIdx.x;
  int quad = t >> 2, lq = t & 3;
  int qi = blk * 64 + quad;  // degree rank
  if (qi >= N) return;
  int row = perm[qi];
  int2 se = prange[qi];
  size_t planeN = (size_t)N * 32;
  const char* __restrict__ hb = (const char*)(hplanes + (size_t)pass * planeN);
  unsigned lofs = (unsigned)lq << 4;
  int s = se.x, e = se.y;
  float acc[8];
  #pragma unroll
  for (int q = 0; q < 8; ++q) acc[q] = 0.f;
  if (s < e) {
    int c[8];
    #pragma unroll
    for (int q = 0; q < 8; ++q) { int x = s + q; c[q] = col[x < e ? x : e - 1]; }
    int i = s;
    for (; i + 8 <= e; i += 8) {
      f16x8 v[8];
      #pragma unroll
      for (int q = 0; q < 8; ++q) v[q] = *(const f16x8*)(hb + ((((unsigned)c[q]) << 6) | lofs));
      #pragma unroll
      for (int q = 0; q < 8; ++q) { int x = i + 8 + q; c[q] = col[x < e ? x : e - 1]; }
      #pragma unroll
      for (int z = 0; z < 8; ++z)
        acc[z] += (((float)v[0][z] + (float)v[1][z]) + ((float)v[2][z] + (float)v[3][z])) +
                  (((float)v[4][z] + (float)v[5][z]) + ((float)v[6][z] + (float)v[7][z]));
    }
    if (i < e) {  // masked tail, c[] holds clamped indices
      f16x8 v[8];
      #pragma unroll
      for (int q = 0; q < 8; ++q) v[q] = *(const f16x8*)(hb + ((((unsigned)c[q]) << 6) | lofs));
      #pragma unroll
      for (int q = 0; q < 8; ++q) {
        float m = (i + q < e) ? 1.f : 0.f;
        #pragma unroll
        for (int z = 0; z < 8; ++z) acc[z] = fmaf(m, (float)v[q][z], acc[z]);
      }
    }
  }
  f16x8 o;
  #pragma unroll
  for (int q = 0; q < 8; ++q) o[q] = (_Float16)acc[q];
  *(f16x8*)(aggplanes + (size_t)pass * planeN + (size_t)row * 32 + lq * 8) = o;
}

// ---------------- dense GEMM over planes: out = relu(concat[agg,h] @ Wcat + b*bscale) ----------------
__global__ __launch_bounds__(256) void gemm_kernel(const _Float16* __restrict__ aggp,
                                                   const _Float16* __restrict__ hp,
                                                   const _Float16* __restrict__ Whi,
                                                   const _Float16* __restrict__ Wlo,
                                                   const float* __restrict__ bias,
                                                   float bscale,
                                                   _Float16* __restrict__ outp, int N) {
  size_t planeN = (size_t)N * 32;
  int wv = threadIdx.x >> 6;
  int lane = threadIdx.x & 63;
  int l16 = lane & 15;
  int khalf = lane >> 4;  // 0..3
  int koff = khalf * 8;
  int row_base = blockIdx.x * 64;
  int col_base = wv * 32;

  f32x4 acc[4][2];
  #pragma unroll
  for (int r = 0; r < 4; r++)
    #pragma unroll
    for (int c = 0; c < 2; c++) acc[r][c] = (f32x4){0.f, 0.f, 0.f, 0.f};

  #pragma unroll
  for (int ks = 0; ks < 8; ++ks) {
    int k0 = ks * 32;
    const _Float16* Abase = (ks < 4) ? (aggp + (size_t)ks * planeN)
                                     : (hp + (size_t)(ks - 4) * planeN);
    f16x8 bh[2], bl[2];
    #pragma unroll
    for (int c = 0; c < 2; c++) {
      int col = col_base + c * 16 + l16;
      bh[c] = *(const f16x8*)(Whi + col * 256 + k0 + koff);
      bl[c] = *(const f16x8*)(Wlo + col * 256 + k0 + koff);
    }
    #pragma unroll
    for (int r = 0; r < 4; r++) {
      int row = row_base + r * 16 + l16;
      if (row >= N) row = N - 1;
      f16x8 a = *(const f16x8*)(Abase + (size_t)row * 32 + koff);
      #pragma unroll
      for (int c = 0; c < 2; c++) {
        acc[r][c] = __builtin_amdgcn_mfma_f32_16x16x32_f16(a, bh[c], acc[r][c], 0, 0, 0);
        acc[r][c] = __builtin_amdgcn_mfma_f32_16x16x32_f16(a, bl[c], acc[r][c], 0, 0, 0);
      }
    }
  }

  #pragma unroll
  for (int r = 0; r < 4; r++) {
    #pragma unroll
    for (int c = 0; c < 2; c++) {
      int cc = col_base + c * 16 + l16;
      float b = bias[cc] * bscale;
      #pragma unroll
      for (int tt = 0; tt < 4; tt++) {
        int row = row_base + r * 16 + khalf * 4 + tt;
        if (row < N) {
          float v = acc[r][c][tt] + b;
          outp[(size_t)wv * planeN + (size_t)row * 32 + (c * 16 + l16)] =
              (_Float16)(v > 0.f ? v : 0.f);
        }
      }
    }
  }
}

// ---------------- fused pool + MLP head (batch sorted, plane reads) ----------------
static __device__ __forceinline__ int lbound(const int* __restrict__ a, int n, int v) {
  int lo = 0, hi = n;
  while (lo < hi) {
    int m = (lo + hi) >> 1;
    if (a[m] < v) lo = m + 1; else hi = m;
  }
  return lo;
}

__global__ __launch_bounds__(128) void poolhead_kernel(const _Float16* __restrict__ h,
                                                       const int* __restrict__ batch,
                                                       const float* __restrict__ fc1W,
                                                       const float* __restrict__ fc1b,
                                                       const float* __restrict__ fc2W,
                                                       const float* __restrict__ fc2b,
                                                       float* __restrict__ out, int N,
                                                       float unscale) {
  int gid = blockIdx.x, j = threadIdx.x;
  int start = lbound(batch, N, gid);
  int end = lbound(batch, N, gid + 1);
  size_t planeN = (size_t)N * 32;
  const _Float16* __restrict__ base = h + (size_t)(j >> 5) * planeN + (j & 31);
  float acc = 0.f;
  int r = start;
  for (; r + 3 < end; r += 4) {
    acc += (float)base[(size_t)r * 32] + (float)base[(size_t)(r + 1) * 32] +
           (float)base[(size_t)(r + 2) * 32] + (float)base[(size_t)(r + 3) * 32];
  }
  for (; r < end; ++r) acc += (float)base[(size_t)r * 32];
  __shared__ float grow[128];
  __shared__ float red[128];
  grow[j] = acc * unscale;
  __syncthreads();
  float a1 = fc1b[j];
  #pragma unroll 8
  for (int k = 0; k < 128; ++k) a1 = fmaf(grow[k], fc1W[k * 128 + j], a1);
  a1 = a1 > 0.f ? a1 : 0.f;
  red[j] = a1 * fc2W[j];
  __syncthreads();
  #pragma unroll
  for (int s2 = 64; s2 > 0; s2 >>= 1) {
    if (j < s2) red[j] += red[j + s2];
    __syncthreads();
  }
  if (j == 0) out[gid] = red[0] + fc2b[0];
}

extern "C" void kernel_launch(void* const* d_in, const int* in_sizes, int n_in,
                              void* d_out, int out_size, void* d_ws, size_t ws_size,
                              hipStream_t stream) {
  const float* x = (const float*)d_in[0];
  const int* edge = (const int*)d_in[1];
  const int* batch = (const int*)d_in[2];
  const int N = in_sizes[0] / 128;
  const int E = in_sizes[1] / 2;
  const int G = out_size;
  const int* esrc = edge;
  const int* edst = edge + E;
  const int NB = (N + 127) >> BSH;  // buckets
  const int nb1 = (E + CHUNK - 1) / CHUNK;

  char* ws = (char*)d_ws;
  size_t off = 0;
  auto alloc = [&](size_t bytes) -> void* {
    void* p = ws + off;
    off = (off + bytes + 255) & ~(size_t)255;
    return p;
  };
  _Float16* x16  = (_Float16*)alloc((size_t)N * 128 * 2);
  _Float16* bufA = (_Float16*)alloc((size_t)N * 128 * 2);
  _Float16* bufB = (_Float16*)alloc((size_t)N * 128 * 2);
  _Float16* agg  = (_Float16*)alloc((size_t)N * 128 * 2);
  _Float16* Whi  = (_Float16*)alloc((size_t)5 * 32768 * 2);
  _Float16* Wlo  = (_Float16*)alloc((size_t)5 * 32768 * 2);
  int* row_ptr   = (int*)alloc((size_t)(N + 1) * 4);
  int* col       = (int*)alloc((size_t)E * 4);
  int2* pairs    = (int2*)alloc((size_t)E * 8);
  int* blkhist   = (int*)alloc((size_t)nb1 * 512 * 4);
  int* base      = (int*)alloc(520 * 4);
  int* gcursor   = (int*)alloc(512 * 4);
  int* dcnt      = (int*)alloc(64 * 4);
  int* dcur      = (int*)alloc(64 * 4);
  int* perm      = (int*)alloc((size_t)N * 4);
  int2* prange   = (int2*)alloc((size_t)N * 8);
  if (off > ws_size) return;  // fail loudly

  hipMemsetAsync(dcnt, 0, 64 * 4, stream);

  bhist_kernel<<<nb1, 256, 0, stream>>>(edst, blkhist, E, NB);
  bscan_kernel<<<1, 512, 0, stream>>>(blkhist, nb1, base, gcursor, NB, E);
  bscatter_kernel<<<nb1, 256, 0, stream>>>(esrc, edst, gcursor, pairs, E, NB);
  bbuild_kernel<<<NB, 256, 0, stream>>>(pairs, base, row_ptr, col, dcnt, N, E);
  dscan_kernel<<<1, 64, 0, stream>>>(dcnt, dcur);
  dscatter_kernel<<<(N + 255) / 256, 256, 0, stream>>>(row_ptr, dcur, perm, prange, N);

  cvt_kernel<<<(N * 32 + 255) / 256, 256, 0, stream>>>(x, x16, N);

  // h'_l = h_l / 8^l keeps fp16 in range; weights *1/8, bias *8^-(l+1), undone at pool.
  const float S = 8.0f;
  W10 wp;
  for (int l = 0; l < 5; ++l) {
    wp.p[l] = (const float*)d_in[4 + 3 * l];
    wp.p[5 + l] = (const float*)d_in[6 + 3 * l];
  }
  prep_kernel<<<640, 256, 0, stream>>>(wp, Whi, Wlo, 1.0f / S);

  const _Float16* hin = x16;
  _Float16* hout = bufA;
  int nbpp = (N + 63) / 64;           // blocks per pass
  int gemm_grid = (N + 63) / 64;
  float bscale = 1.0f;
  for (int l = 0; l < 5; ++l) {
    bscale /= S;
    spmm_kernel<<<4 * nbpp, 256, 0, stream>>>(hin, perm, prange, col, agg, N, nbpp);
    gemm_kernel<<<gemm_grid, 256, 0, stream>>>(agg, hin,
                                               Whi + (size_t)l * 32768, Wlo + (size_t)l * 32768,
                                               (const float*)d_in[5 + 3 * l], bscale, hout, N);
    hin = hout;
    hout = (hout == bufA) ? bufB : bufA;
  }
  poolhead_kernel<<<G, 128, 0, stream>>>(hin, batch,
                                         (const float*)d_in[19], (const float*)d_in[20],
                                         (const float*)d_in[21], (const float*)d_in[22],
                                         (float*)d_out, N, 32768.0f);
}

// Round 11
// 419.470 us; speedup vs baseline: 1.6068x; 1.6068x over previous
//
#include <hip/hip_runtime.h>
#include <hip/hip_bf16.h>

typedef __attribute__((ext_vector_type(4))) float f32x4;
typedef __attribute__((ext_vector_type(8))) _Float16 f16x8;
typedef __attribute__((ext_vector_type(4))) _Float16 f16x4;

#define CHUNK 4096   // edges per pass-1 block
#define BSH 7        // nodes per bucket = 128
#define CAP 4096     // max edges per bucket handled in LDS fast path

// h layout: 4 feature-quarter planes, plane p holds columns [32p,32p+32) of all
// rows contiguously: hp[p*N*32 + r*32 + c]. A plane (3.2 MB) fits each XCD L2.

// ---------------- fp32 -> fp16 convert into planes ----------------
__global__ __launch_bounds__(256) void cvt_kernel(const float* __restrict__ x,
                                                  _Float16* __restrict__ hp, int N) {
  int i = blockIdx.x * blockDim.x + threadIdx.x;  // over N*32 quads of 4 elems
  if (i < N * 32) {
    int r = i >> 5, jg = i & 31;
    float4 v = *(const float4*)(x + (size_t)r * 128 + jg * 4);
    f16x4 o = {(_Float16)v.x, (_Float16)v.y, (_Float16)v.z, (_Float16)v.w};
    int plane = jg >> 3, wc = (jg & 7) * 4;
    *(f16x4*)(hp + (size_t)plane * N * 32 + (size_t)r * 32 + wc) = o;
  }
}

// ---------------- CSR build: bucketed counting sort ----------------
__global__ __launch_bounds__(256) void bhist_kernel(const int* __restrict__ dst,
                                                    int* __restrict__ blkhist, int E, int nb) {
  __shared__ int l[512];
  int t = threadIdx.x;
  for (int i = t; i < 512; i += 256) l[i] = 0;
  __syncthreads();
  int cbase = blockIdx.x * CHUNK;
  #pragma unroll
  for (int i = 0; i < CHUNK / 256; ++i) {
    int idx = cbase + i * 256 + t;
    if (idx < E) atomicAdd(&l[dst[idx] >> BSH], 1);
  }
  __syncthreads();
  for (int i = t; i < 512; i += 256) blkhist[blockIdx.x * 512 + i] = l[i];
}

__global__ __launch_bounds__(512) void bscan_kernel(const int* __restrict__ blkhist, int nblk,
                                                    int* __restrict__ base,
                                                    int* __restrict__ gcursor, int nb, int E) {
  __shared__ int wsum[8], wpre[8];
  int t = threadIdx.x, lane = t & 63, w = t >> 6;
  int v = 0;
  int b = 0;
  for (; b + 4 <= nblk; b += 4)
    v += blkhist[b * 512 + t] + blkhist[(b + 1) * 512 + t] +
         blkhist[(b + 2) * 512 + t] + blkhist[(b + 3) * 512 + t];
  for (; b < nblk; ++b) v += blkhist[b * 512 + t];
  int incl = v;
  #pragma unroll
  for (int o = 1; o < 64; o <<= 1) {
    int x = __shfl_up(incl, o, 64);
    if (lane >= o) incl += x;
  }
  if (lane == 63) wsum[w] = incl;
  __syncthreads();
  if (t == 0) {
    int run = 0;
    #pragma unroll
    for (int q = 0; q < 8; ++q) { wpre[q] = run; run += wsum[q]; }
  }
  __syncthreads();
  int excl = wpre[w] + incl - v;
  if (t < nb) { base[t] = excl; gcursor[t] = excl; }
  if (t == 0) base[nb] = E;
}

__global__ __launch_bounds__(256) void bscatter_kernel(const int* __restrict__ src,
                                                       const int* __restrict__ dst,
                                                       int* __restrict__ gcursor,
                                                       int2* __restrict__ pairs, int E, int nb) {
  __shared__ int lcnt[512], lstart[512], lpos[512], lgbase[512];
  __shared__ int2 lp[CHUNK];
  __shared__ int wsum[4], wpre[4];
  int t = threadIdx.x, lane = t & 63, w = t >> 6;
  for (int i = t; i < 512; i += 256) lcnt[i] = 0;
  __syncthreads();
  int cbase = blockIdx.x * CHUNK;
  int m = E - cbase; if (m > CHUNK) m = CHUNK;
  #pragma unroll
  for (int i = 0; i < CHUNK / 256; ++i) {
    int idx = i * 256 + t;
    if (idx < m) atomicAdd(&lcnt[dst[cbase + idx] >> BSH], 1);
  }
  __syncthreads();
  int c0 = lcnt[2 * t], c1 = lcnt[2 * t + 1];
  int s = c0 + c1, incl = s;
  #pragma unroll
  for (int o = 1; o < 64; o <<= 1) {
    int x = __shfl_up(incl, o, 64);
    if (lane >= o) incl += x;
  }
  if (lane == 63) wsum[w] = incl;
  __syncthreads();
  if (t == 0) {
    int run = 0;
    #pragma unroll
    for (int q = 0; q < 4; ++q) { wpre[q] = run; run += wsum[q]; }
  }
  __syncthreads();
  int excl = wpre[w] + incl - s;
  lstart[2 * t] = excl;          lpos[2 * t] = excl;
  lstart[2 * t + 1] = excl + c0; lpos[2 * t + 1] = excl + c0;
  if (2 * t < nb && c0 > 0) lgbase[2 * t] = atomicAdd(&gcursor[2 * t], c0);
  if (2 * t + 1 < nb && c1 > 0) lgbase[2 * t + 1] = atomicAdd(&gcursor[2 * t + 1], c1);
  __syncthreads();
  #pragma unroll
  for (int i = 0; i < CHUNK / 256; ++i) {
    int idx = i * 256 + t;
    if (idx < m) {
      int d = dst[cbase + idx], sv = src[cbase + idx];
      int p = atomicAdd(&lpos[d >> BSH], 1);
      lp[p] = make_int2(sv, d);
    }
  }
  __syncthreads();
  for (int i = t; i < m; i += 256) {
    int2 pr = lp[i];
    int b = pr.y >> BSH;
    pairs[lgbase[b] + (i - lstart[b])] = pr;
  }
}

__global__ __launch_bounds__(256) void bbuild_kernel(const int2* __restrict__ pairs,
                                                     const int* __restrict__ base,
                                                     int* __restrict__ row_ptr,
                                                     int* __restrict__ col, int N, int E) {
  __shared__ int cnt[128], cur[128], w2[2];
  __shared__ int cl[CAP];
  int b = blockIdx.x, t = threadIdx.x;
  int mb = base[b], me = base[b + 1], m = me - mb;
  if (t < 128) cnt[t] = 0;
  __syncthreads();
  for (int i = t; i < m; i += 256) atomicAdd(&cnt[pairs[mb + i].y & 127], 1);
  __syncthreads();
  int v = 0, incl = 0;
  if (t < 128) {
    v = cnt[t]; incl = v;
    #pragma unroll
    for (int o = 1; o < 64; o <<= 1) {
      int x = __shfl_up(incl, o, 64);
      if ((t & 63) >= o) incl += x;
    }
    if ((t & 63) == 63) w2[t >> 6] = incl;
  }
  __syncthreads();
  if (t < 128) {
    int excl = incl - v + ((t & 64) ? w2[0] : 0);
    cur[t] = excl;
    int node = (b << BSH) + t;
    if (node < N) row_ptr[node] = mb + excl;
  }
  if (b == 0 && t == 0) row_ptr[N] = E;
  __syncthreads();
  if (m <= CAP) {
    for (int i = t; i < m; i += 256) {
      int2 p = pairs[mb + i];
      int pos = atomicAdd(&cur[p.y & 127], 1);
      cl[pos] = p.x;
    }
    __syncthreads();
    for (int i = t; i < m; i += 256) col[mb + i] = cl[i];
  } else {
    for (int i = t; i < m; i += 256) {
      int2 p = pairs[mb + i];
      int pos = atomicAdd(&cur[p.y & 127], 1);
      col[mb + pos] = p.x;
    }
  }
}

// ---------------- degree-sort (contention-free): per-block hist -> scan -> scatter ----------------
// 1024 rows per block; degrees binned to 0..63.
__global__ __launch_bounds__(256) void dhist_kernel(const int* __restrict__ row_ptr,
                                                    int* __restrict__ blkdh, int N) {
  __shared__ int l[64];
  int t = threadIdx.x;
  if (t < 64) l[t] = 0;
  __syncthreads();
  int base = blockIdx.x * 1024;
  #pragma unroll
  for (int i = 0; i < 4; ++i) {
    int r = base + i * 256 + t;
    if (r < N) {
      int deg = row_ptr[r + 1] - row_ptr[r];
      atomicAdd(&l[deg < 63 ? deg : 63], 1);
    }
  }
  __syncthreads();
  if (t < 64) blkdh[blockIdx.x * 64 + t] = l[t];
}

// 64 threads: bin-major scan -> per-block per-bin global offsets
__global__ void dscan_kernel(const int* __restrict__ blkdh, int nblk,
                             int* __restrict__ blkoff) {
  int t = threadIdx.x;  // 0..63 = bin
  int tot = 0;
  for (int b = 0; b < nblk; ++b) tot += blkdh[b * 64 + t];
  int incl = tot;
  #pragma unroll
  for (int o = 1; o < 64; o <<= 1) {
    int x = __shfl_up(incl, o, 64);
    if (t >= o) incl += x;
  }
  int run = incl - tot;  // global exclusive base of bin t
  for (int b = 0; b < nblk; ++b) {
    int c = blkdh[b * 64 + t];
    blkoff[b * 64 + t] = run;
    run += c;
  }
}

__global__ __launch_bounds__(256) void dscatter_kernel(const int* __restrict__ row_ptr,
                                                       const int* __restrict__ blkoff,
                                                       int* __restrict__ perm,
                                                       int2* __restrict__ prange, int N) {
  __shared__ int cur[64];
  int t = threadIdx.x;
  if (t < 64) cur[t] = blkoff[blockIdx.x * 64 + t];
  __syncthreads();
  int base = blockIdx.x * 1024;
  #pragma unroll
  for (int i = 0; i < 4; ++i) {
    int r = base + i * 256 + t;
    if (r < N) {
      int s = row_ptr[r], e = row_ptr[r + 1];
      int deg = e - s;
      int b = deg < 63 ? deg : 63;
      int pos = atomicAdd(&cur[b], 1);
      perm[pos] = r;
      prange[pos] = make_int2(s, e);
    }
  }
}

// ---------------- weight prep: all 5 layers in one launch ----------------
struct W10 { const float* p[10]; };  // p[0..4]=Wrel, p[5..9]=Wroot

__global__ __launch_bounds__(256) void prep_kernel(W10 wp, _Float16* __restrict__ Whi,
                                                   _Float16* __restrict__ Wlo, float wscale) {
  int l = blockIdx.x >> 7;
  int idx = (blockIdx.x & 127) * 256 + threadIdx.x;  // col*256 + k
  int col = idx >> 8;
  int k = idx & 255;
  const float* __restrict__ Wrel = wp.p[l];
  const float* __restrict__ Wroot = wp.p[5 + l];
  float v = (k < 128) ? Wrel[k * 128 + col] : Wroot[(k - 128) * 128 + col];
  v *= wscale;
  _Float16 hi = (_Float16)v;
  _Float16 lo = (_Float16)(v - (float)hi);
  Whi[(size_t)l * 32768 + idx] = hi;
  Wlo[(size_t)l * 32768 + idx] = lo;
}

// ---------------- SpMM over feature-quarter planes, degree-sorted rows ----------------
__global__ __launch_bounds__(256) void spmm_kernel(const _Float16* __restrict__ hplanes,
                                                   const int* __restrict__ perm,
                                                   const int2* __restrict__ prange,
                                                   const int* __restrict__ col,
                                                   _Float16* __restrict__ aggplanes,
                                                   int N, int nbpp) {
  int pass = blockIdx.x / nbpp;
  int blk = blockIdx.x - pass * nbpp;
  int t = threadIdx.x;
  int quad = t >> 2, lq = t & 3;
  int qi = blk * 64 + quad;  // degree rank
  if (qi >= N) return;
  int row = perm[qi];
  int2 se = prange[qi];
  size_t planeN = (size_t)N * 32;
  const char* __restrict__ hb = (const char*)(hplanes + (size_t)pass * planeN);
  unsigned lofs = (unsigned)lq << 4;
  int s = se.x, e = se.y;
  float acc[8];
  #pragma unroll
  for (int q = 0; q < 8; ++q) acc[q] = 0.f;
  if (s < e) {
    int c[8];
    #pragma unroll
    for (int q = 0; q < 8; ++q) { int x = s + q; c[q] = col[x < e ? x : e - 1]; }
    int i = s;
    for (; i + 8 <= e; i += 8) {
      f16x8 v[8];
      #pragma unroll
      for (int q = 0; q < 8; ++q) v[q] = *(const f16x8*)(hb + ((((unsigned)c[q]) << 6) | lofs));
      #pragma unroll
      for (int q = 0; q < 8; ++q) { int x = i + 8 + q; c[q] = col[x < e ? x : e - 1]; }
      #pragma unroll
      for (int z = 0; z < 8; ++z)
        acc[z] += (((float)v[0][z] + (float)v[1][z]) + ((float)v[2][z] + (float)v[3][z])) +
                  (((float)v[4][z] + (float)v[5][z]) + ((float)v[6][z] + (float)v[7][z]));
    }
    if (i < e) {  // masked tail, c[] holds clamped indices
      f16x8 v[8];
      #pragma unroll
      for (int q = 0; q < 8; ++q) v[q] = *(const f16x8*)(hb + ((((unsigned)c[q]) << 6) | lofs));
      #pragma unroll
      for (int q = 0; q < 8; ++q) {
        float m = (i + q < e) ? 1.f : 0.f;
        #pragma unroll
        for (int z = 0; z < 8; ++z) acc[z] = fmaf(m, (float)v[q][z], acc[z]);
      }
    }
  }
  f16x8 o;
  #pragma unroll
  for (int q = 0; q < 8; ++q) o[q] = (_Float16)acc[q];
  *(f16x8*)(aggplanes + (size_t)pass * planeN + (size_t)row * 32 + lq * 8) = o;
}

// ---------------- dense GEMM over planes: out = relu(concat[agg,h] @ Wcat + b*bscale) ----------------
__global__ __launch_bounds__(256) void gemm_kernel(const _Float16* __restrict__ aggp,
                                                   const _Float16* __restrict__ hp,
                                                   const _Float16* __restrict__ Whi,
                                                   const _Float16* __restrict__ Wlo,
                                                   const float* __restrict__ bias,
                                                   float bscale,
                                                   _Float16* __restrict__ outp, int N) {
  size_t planeN = (size_t)N * 32;
  int wv = threadIdx.x >> 6;
  int lane = threadIdx.x & 63;
  int l16 = lane & 15;
  int khalf = lane >> 4;  // 0..3
  int koff = khalf * 8;
  int row_base = blockIdx.x * 64;
  int col_base = wv * 32;

  f32x4 acc[4][2];
  #pragma unroll
  for (int r = 0; r < 4; r++)
    #pragma unroll
    for (int c = 0; c < 2; c++) acc[r][c] = (f32x4){0.f, 0.f, 0.f, 0.f};

  #pragma unroll
  for (int ks = 0; ks < 8; ++ks) {
    int k0 = ks * 32;
    const _Float16* Abase = (ks < 4) ? (aggp + (size_t)ks * planeN)
                                     : (hp + (size_t)(ks - 4) * planeN);
    f16x8 bh[2], bl[2];
    #pragma unroll
    for (int c = 0; c < 2; c++) {
      int col = col_base + c * 16 + l16;
      bh[c] = *(const f16x8*)(Whi + col * 256 + k0 + koff);
      bl[c] = *(const f16x8*)(Wlo + col * 256 + k0 + koff);
    }
    #pragma unroll
    for (int r = 0; r < 4; r++) {
      int row = row_base + r * 16 + l16;
      if (row >= N) row = N - 1;
      f16x8 a = *(const f16x8*)(Abase + (size_t)row * 32 + koff);
      #pragma unroll
      for (int c = 0; c < 2; c++) {
        acc[r][c] = __builtin_amdgcn_mfma_f32_16x16x32_f16(a, bh[c], acc[r][c], 0, 0, 0);
        acc[r][c] = __builtin_amdgcn_mfma_f32_16x16x32_f16(a, bl[c], acc[r][c], 0, 0, 0);
      }
    }
  }

  #pragma unroll
  for (int r = 0; r < 4; r++) {
    #pragma unroll
    for (int c = 0; c < 2; c++) {
      int cc = col_base + c * 16 + l16;
      float b = bias[cc] * bscale;
      #pragma unroll
      for (int tt = 0; tt < 4; tt++) {
        int row = row_base + r * 16 + khalf * 4 + tt;
        if (row < N) {
          float v = acc[r][c][tt] + b;
          outp[(size_t)wv * planeN + (size_t)row * 32 + (c * 16 + l16)] =
              (_Float16)(v > 0.f ? v : 0.f);
        }
      }
    }
  }
}

// ---------------- fused pool + MLP head (batch sorted, plane reads) ----------------
static __device__ __forceinline__ int lbound(const int* __restrict__ a, int n, int v) {
  int lo = 0, hi = n;
  while (lo < hi) {
    int m = (lo + hi) >> 1;
    if (a[m] < v) lo = m + 1; else hi = m;
  }
  return lo;
}

__global__ __launch_bounds__(128) void poolhead_kernel(const _Float16* __restrict__ h,
                                                       const int* __restrict__ batch,
                                                       const float* __restrict__ fc1W,
                                                       const float* __restrict__ fc1b,
                                                       const float* __restrict__ fc2W,
                                                       const float* __restrict__ fc2b,
                                                       float* __restrict__ out, int N,
                                                       float unscale) {
  int gid = blockIdx.x, j = threadIdx.x;
  int start = lbound(batch, N, gid);
  int end = lbound(batch, N, gid + 1);
  size_t planeN = (size_t)N * 32;
  const _Float16* __restrict__ base = h + (size_t)(j >> 5) * planeN + (j & 31);
  float acc = 0.f;
  int r = start;
  for (; r + 3 < end; r += 4) {
    acc += (float)base[(size_t)r * 32] + (float)base[(size_t)(r + 1) * 32] +
           (float)base[(size_t)(r + 2) * 32] + (float)base[(size_t)(r + 3) * 32];
  }
  for (; r < end; ++r) acc += (float)base[(size_t)r * 32];
  __shared__ float grow[128];
  __shared__ float red[128];
  grow[j] = acc * unscale;
  __syncthreads();
  float a1 = fc1b[j];
  #pragma unroll 8
  for (int k = 0; k < 128; ++k) a1 = fmaf(grow[k], fc1W[k * 128 + j], a1);
  a1 = a1 > 0.f ? a1 : 0.f;
  red[j] = a1 * fc2W[j];
  __syncthreads();
  #pragma unroll
  for (int s2 = 64; s2 > 0; s2 >>= 1) {
    if (j < s2) red[j] += red[j + s2];
    __syncthreads();
  }
  if (j == 0) out[gid] = red[0] + fc2b[0];
}

extern "C" void kernel_launch(void* const* d_in, const int* in_sizes, int n_in,
                              void* d_out, int out_size, void* d_ws, size_t ws_size,
                              hipStream_t stream) {
  const float* x = (const float*)d_in[0];
  const int* edge = (const int*)d_in[1];
  const int* batch = (const int*)d_in[2];
  const int N = in_sizes[0] / 128;
  const int E = in_sizes[1] / 2;
  const int G = out_size;
  const int* esrc = edge;
  const int* edst = edge + E;
  const int NB = (N + 127) >> BSH;  // buckets
  const int nb1 = (E + CHUNK - 1) / CHUNK;
  const int nbd = (N + 1023) / 1024;  // degree-sort blocks

  char* ws = (char*)d_ws;
  size_t off = 0;
  auto alloc = [&](size_t bytes) -> void* {
    void* p = ws + off;
    off = (off + bytes + 255) & ~(size_t)255;
    return p;
  };
  _Float16* x16  = (_Float16*)alloc((size_t)N * 128 * 2);
  _Float16* bufA = (_Float16*)alloc((size_t)N * 128 * 2);
  _Float16* bufB = (_Float16*)alloc((size_t)N * 128 * 2);
  _Float16* agg  = (_Float16*)alloc((size_t)N * 128 * 2);
  _Float16* Whi  = (_Float16*)alloc((size_t)5 * 32768 * 2);
  _Float16* Wlo  = (_Float16*)alloc((size_t)5 * 32768 * 2);
  int* row_ptr   = (int*)alloc((size_t)(N + 1) * 4);
  int* col       = (int*)alloc((size_t)E * 4);
  int2* pairs    = (int2*)alloc((size_t)E * 8);
  int* blkhist   = (int*)alloc((size_t)nb1 * 512 * 4);
  int* base      = (int*)alloc(520 * 4);
  int* gcursor   = (int*)alloc(512 * 4);
  int* blkdh     = (int*)alloc((size_t)nbd * 64 * 4);
  int* blkoff    = (int*)alloc((size_t)nbd * 64 * 4);
  int* perm      = (int*)alloc((size_t)N * 4);
  int2* prange   = (int2*)alloc((size_t)N * 8);
  if (off > ws_size) return;  // fail loudly

  bhist_kernel<<<nb1, 256, 0, stream>>>(edst, blkhist, E, NB);
  bscan_kernel<<<1, 512, 0, stream>>>(blkhist, nb1, base, gcursor, NB, E);
  bscatter_kernel<<<nb1, 256, 0, stream>>>(esrc, edst, gcursor, pairs, E, NB);
  bbuild_kernel<<<NB, 256, 0, stream>>>(pairs, base, row_ptr, col, N, E);
  dhist_kernel<<<nbd, 256, 0, stream>>>(row_ptr, blkdh, N);
  dscan_kernel<<<1, 64, 0, stream>>>(blkdh, nbd, blkoff);
  dscatter_kernel<<<nbd, 256, 0, stream>>>(row_ptr, blkoff, perm, prange, N);

  cvt_kernel<<<(N * 32 + 255) / 256, 256, 0, stream>>>(x, x16, N);

  // h'_l = h_l / 8^l keeps fp16 in range; weights *1/8, bias *8^-(l+1), undone at pool.
  const float S = 8.0f;
  W10 wp;
  for (int l = 0; l < 5; ++l) {
    wp.p[l] = (const float*)d_in[4 + 3 * l];
    wp.p[5 + l] = (const float*)d_in[6 + 3 * l];
  }
  prep_kernel<<<640, 256, 0, stream>>>(wp, Whi, Wlo, 1.0f / S);

  const _Float16* hin = x16;
  _Float16* hout = bufA;
  int nbpp = (N + 63) / 64;           // blocks per pass
  int gemm_grid = (N + 63) / 64;
  float bscale = 1.0f;
  for (int l = 0; l < 5; ++l) {
    bscale /= S;
    spmm_kernel<<<4 * nbpp, 256, 0, stream>>>(hin, perm, prange, col, agg, N, nbpp);
    gemm_kernel<<<gemm_grid, 256, 0, stream>>>(agg, hin,
                                               Whi + (size_t)l * 32768, Wlo + (size_t)l * 32768,
                                               (const float*)d_in[5 + 3 * l], bscale, hout, N);
    hin = hout;
    hout = (hout == bufA) ? bufB : bufA;
  }
  poolhead_kernel<<<G, 128, 0, stream>>>(hin, batch,
                                         (const float*)d_in[19], (const float*)d_in[20],
                                         (const float*)d_in[21], (const float*)d_in[22],
                                         (float*)d_out, N, 32768.0f);
}

// Round 12
// 391.504 us; speedup vs baseline: 1.7215x; 1.0714x over previous
//
#include <hip/hip_runtime.h>
#include <hip/hip_bf16.h>

typedef __attribute__((ext_vector_type(4))) float f32x4;
typedef __attribute__((ext_vector_type(8))) _Float16 f16x8;
typedef __attribute__((ext_vector_type(4))) _Float16 f16x4;

#define CHUNK 4096   // edges per pass-1 block
#define BSH 7        // nodes per bucket = 128
#define CAP 4096     // max edges per bucket handled in LDS fast path

// h layout: 4 feature-quarter planes, plane p holds columns [32p,32p+32) of all
// rows contiguously: hp[p*N*32 + r*32 + c]. A plane (3.2 MB) fits each XCD L2.

// direct-to-LDS 16B per-lane load: LDS dest = uniform base + lane*16
static __device__ __forceinline__ void gload_lds16(const void* g, void* l) {
  __builtin_amdgcn_global_load_lds(
      (const __attribute__((address_space(1))) void*)g,
      (__attribute__((address_space(3))) void*)l, 16, 0, 0);
}

// ---------------- fp32 -> fp16 convert into planes ----------------
__global__ __launch_bounds__(256) void cvt_kernel(const float* __restrict__ x,
                                                  _Float16* __restrict__ hp, int N) {
  int i = blockIdx.x * blockDim.x + threadIdx.x;  // over N*32 quads of 4 elems
  if (i < N * 32) {
    int r = i >> 5, jg = i & 31;
    float4 v = *(const float4*)(x + (size_t)r * 128 + jg * 4);
    f16x4 o = {(_Float16)v.x, (_Float16)v.y, (_Float16)v.z, (_Float16)v.w};
    int plane = jg >> 3, wc = (jg & 7) * 4;
    *(f16x4*)(hp + (size_t)plane * N * 32 + (size_t)r * 32 + wc) = o;
  }
}

// ---------------- CSR build: bucketed counting sort ----------------
__global__ __launch_bounds__(256) void bhist_kernel(const int* __restrict__ dst,
                                                    int* __restrict__ blkhist, int E, int nb) {
  __shared__ int l[512];
  int t = threadIdx.x;
  for (int i = t; i < 512; i += 256) l[i] = 0;
  __syncthreads();
  int cbase = blockIdx.x * CHUNK;
  #pragma unroll
  for (int i = 0; i < CHUNK / 256; ++i) {
    int idx = cbase + i * 256 + t;
    if (idx < E) atomicAdd(&l[dst[idx] >> BSH], 1);
  }
  __syncthreads();
  for (int i = t; i < 512; i += 256) blkhist[blockIdx.x * 512 + i] = l[i];
}

__global__ __launch_bounds__(512) void bscan_kernel(const int* __restrict__ blkhist, int nblk,
                                                    int* __restrict__ base,
                                                    int* __restrict__ gcursor, int nb, int E) {
  __shared__ int wsum[8], wpre[8];
  int t = threadIdx.x, lane = t & 63, w = t >> 6;
  int v = 0;
  int b = 0;
  for (; b + 4 <= nblk; b += 4)
    v += blkhist[b * 512 + t] + blkhist[(b + 1) * 512 + t] +
         blkhist[(b + 2) * 512 + t] + blkhist[(b + 3) * 512 + t];
  for (; b < nblk; ++b) v += blkhist[b * 512 + t];
  int incl = v;
  #pragma unroll
  for (int o = 1; o < 64; o <<= 1) {
    int x = __shfl_up(incl, o, 64);
    if (lane >= o) incl += x;
  }
  if (lane == 63) wsum[w] = incl;
  __syncthreads();
  if (t == 0) {
    int run = 0;
    #pragma unroll
    for (int q = 0; q < 8; ++q) { wpre[q] = run; run += wsum[q]; }
  }
  __syncthreads();
  int excl = wpre[w] + incl - v;
  if (t < nb) { base[t] = excl; gcursor[t] = excl; }
  if (t == 0) base[nb] = E;
}

__global__ __launch_bounds__(256) void bscatter_kernel(const int* __restrict__ src,
                                                       const int* __restrict__ dst,
                                                       int* __restrict__ gcursor,
                                                       int2* __restrict__ pairs, int E, int nb) {
  __shared__ int lcnt[512], lstart[512], lpos[512], lgbase[512];
  __shared__ int2 lp[CHUNK];
  __shared__ int wsum[4], wpre[4];
  int t = threadIdx.x, lane = t & 63, w = t >> 6;
  for (int i = t; i < 512; i += 256) lcnt[i] = 0;
  __syncthreads();
  int cbase = blockIdx.x * CHUNK;
  int m = E - cbase; if (m > CHUNK) m = CHUNK;
  #pragma unroll
  for (int i = 0; i < CHUNK / 256; ++i) {
    int idx = i * 256 + t;
    if (idx < m) atomicAdd(&lcnt[dst[cbase + idx] >> BSH], 1);
  }
  __syncthreads();
  int c0 = lcnt[2 * t], c1 = lcnt[2 * t + 1];
  int s = c0 + c1, incl = s;
  #pragma unroll
  for (int o = 1; o < 64; o <<= 1) {
    int x = __shfl_up(incl, o, 64);
    if (lane >= o) incl += x;
  }
  if (lane == 63) wsum[w] = incl;
  __syncthreads();
  if (t == 0) {
    int run = 0;
    #pragma unroll
    for (int q = 0; q < 4; ++q) { wpre[q] = run; run += wsum[q]; }
  }
  __syncthreads();
  int excl = wpre[w] + incl - s;
  lstart[2 * t] = excl;          lpos[2 * t] = excl;
  lstart[2 * t + 1] = excl + c0; lpos[2 * t + 1] = excl + c0;
  if (2 * t < nb && c0 > 0) lgbase[2 * t] = atomicAdd(&gcursor[2 * t], c0);
  if (2 * t + 1 < nb && c1 > 0) lgbase[2 * t + 1] = atomicAdd(&gcursor[2 * t + 1], c1);
  __syncthreads();
  #pragma unroll
  for (int i = 0; i < CHUNK / 256; ++i) {
    int idx = i * 256 + t;
    if (idx < m) {
      int d = dst[cbase + idx], sv = src[cbase + idx];
      int p = atomicAdd(&lpos[d >> BSH], 1);
      lp[p] = make_int2(sv, d);
    }
  }
  __syncthreads();
  for (int i = t; i < m; i += 256) {
    int2 pr = lp[i];
    int b = pr.y >> BSH;
    pairs[lgbase[b] + (i - lstart[b])] = pr;
  }
}

__global__ __launch_bounds__(256) void bbuild_kernel(const int2* __restrict__ pairs,
                                                     const int* __restrict__ base,
                                                     int* __restrict__ row_ptr,
                                                     int* __restrict__ col, int N, int E) {
  __shared__ int cnt[128], cur[128], w2[2];
  __shared__ int cl[CAP];
  int b = blockIdx.x, t = threadIdx.x;
  int mb = base[b], me = base[b + 1], m = me - mb;
  if (t < 128) cnt[t] = 0;
  __syncthreads();
  for (int i = t; i < m; i += 256) atomicAdd(&cnt[pairs[mb + i].y & 127], 1);
  __syncthreads();
  int v = 0, incl = 0;
  if (t < 128) {
    v = cnt[t]; incl = v;
    #pragma unroll
    for (int o = 1; o < 64; o <<= 1) {
      int x = __shfl_up(incl, o, 64);
      if ((t & 63) >= o) incl += x;
    }
    if ((t & 63) == 63) w2[t >> 6] = incl;
  }
  __syncthreads();
  if (t < 128) {
    int excl = incl - v + ((t & 64) ? w2[0] : 0);
    cur[t] = excl;
    int node = (b << BSH) + t;
    if (node < N) row_ptr[node] = mb + excl;
  }
  if (b == 0 && t == 0) row_ptr[N] = E;
  __syncthreads();
  if (m <= CAP) {
    for (int i = t; i < m; i += 256) {
      int2 p = pairs[mb + i];
      int pos = atomicAdd(&cur[p.y & 127], 1);
      cl[pos] = p.x;
    }
    __syncthreads();
    for (int i = t; i < m; i += 256) col[mb + i] = cl[i];
  } else {
    for (int i = t; i < m; i += 256) {
      int2 p = pairs[mb + i];
      int pos = atomicAdd(&cur[p.y & 127], 1);
      col[mb + pos] = p.x;
    }
  }
}

// ---------------- weight prep: all 5 layers in one launch ----------------
struct W10 { const float* p[10]; };  // p[0..4]=Wrel, p[5..9]=Wroot

__global__ __launch_bounds__(256) void prep_kernel(W10 wp, _Float16* __restrict__ Whi,
                                                   _Float16* __restrict__ Wlo, float wscale) {
  int l = blockIdx.x >> 7;
  int idx = (blockIdx.x & 127) * 256 + threadIdx.x;  // col*256 + k
  int col = idx >> 8;
  int k = idx & 255;
  const float* __restrict__ Wrel = wp.p[l];
  const float* __restrict__ Wroot = wp.p[5 + l];
  float v = (k < 128) ? Wrel[k * 128 + col] : Wroot[(k - 128) * 128 + col];
  v *= wscale;
  _Float16 hi = (_Float16)v;
  _Float16 lo = (_Float16)(v - (float)hi);
  Whi[(size_t)l * 32768 + idx] = hi;
  Wlo[(size_t)l * 32768 + idx] = lo;
}

// ---------------- SpMM over planes via direct-to-LDS DMA gather ----------------
// pass p: 1 line (64B) per edge from plane p. Quad (4 lanes) owns one dst row.
// Per wave-instr: 16 quads x 64B staged to LDS; 8-deep batch, drain, accumulate.
__global__ __launch_bounds__(256) void spmm_kernel(const _Float16* __restrict__ hplanes,
                                                   const int* __restrict__ row_ptr,
                                                   const int* __restrict__ col,
                                                   _Float16* __restrict__ aggplanes,
                                                   int N, int nbpp) {
  __shared__ _Float16 stage[4][8][64][8];  // 32KB: [wave][k][lane][8 halves]
  int pass = blockIdx.x / nbpp;
  int blk = blockIdx.x - pass * nbpp;
  int t = threadIdx.x;
  int w = t >> 6, lane = t & 63;
  int quad = lane >> 2, sub = lane & 3;
  int row = blk * 64 + w * 16 + quad;
  size_t planeN = (size_t)N * 32;
  const char* __restrict__ hb = (const char*)(hplanes + (size_t)pass * planeN);
  int s = 0, e = 0;
  if (row < N) { s = row_ptr[row]; e = row_ptr[row + 1]; }
  float acc[8];
  #pragma unroll
  for (int q = 0; q < 8; ++q) acc[q] = 0.f;

  int i = s;
  while (__any(i < e)) {
    if (i < e) {
      #pragma unroll
      for (int k = 0; k < 8; ++k) {
        int x = i + k;
        int c = col[x < e ? x : e - 1];
        gload_lds16(hb + ((((unsigned)c) << 6) | ((unsigned)sub << 4)),
                    &stage[w][k][0][0]);
      }
    }
    asm volatile("s_waitcnt vmcnt(0)" ::: "memory");
    __builtin_amdgcn_sched_barrier(0);
    if (i < e) {
      #pragma unroll
      for (int k = 0; k < 8; ++k) {
        f16x8 v = *(const f16x8*)&stage[w][k][lane][0];
        float m = (i + k < e) ? 1.f : 0.f;
        #pragma unroll
        for (int z = 0; z < 8; ++z) acc[z] = fmaf(m, (float)v[z], acc[z]);
      }
    }
    i += 8;
  }

  if (row < N) {
    // each lane holds 8 accumulated features of its quad's row? No: each lane's
    // acc covers its own 16B sub-slice (sub*8 features) of the row's 32.
    f16x8 o;
    #pragma unroll
    for (int q = 0; q < 8; ++q) o[q] = (_Float16)acc[q];
    *(f16x8*)(aggplanes + (size_t)pass * planeN + (size_t)row * 32 + sub * 8) = o;
  }
}

// ---------------- dense GEMM over planes: out = relu(concat[agg,h] @ Wcat + b*bscale) ----------------
__global__ __launch_bounds__(256) void gemm_kernel(const _Float16* __restrict__ aggp,
                                                   const _Float16* __restrict__ hp,
                                                   const _Float16* __restrict__ Whi,
                                                   const _Float16* __restrict__ Wlo,
                                                   const float* __restrict__ bias,
                                                   float bscale,
                                                   _Float16* __restrict__ outp, int N) {
  size_t planeN = (size_t)N * 32;
  int wv = threadIdx.x >> 6;
  int lane = threadIdx.x & 63;
  int l16 = lane & 15;
  int khalf = lane >> 4;  // 0..3
  int koff = khalf * 8;
  int row_base = blockIdx.x * 64;
  int col_base = wv * 32;

  f32x4 acc[4][2];
  #pragma unroll
  for (int r = 0; r < 4; r++)
    #pragma unroll
    for (int c = 0; c < 2; c++) acc[r][c] = (f32x4){0.f, 0.f, 0.f, 0.f};

  #pragma unroll
  for (int ks = 0; ks < 8; ++ks) {
    int k0 = ks * 32;
    const _Float16* Abase = (ks < 4) ? (aggp + (size_t)ks * planeN)
                                     : (hp + (size_t)(ks - 4) * planeN);
    f16x8 bh[2], bl[2];
    #pragma unroll
    for (int c = 0; c < 2; c++) {
      int col = col_base + c * 16 + l16;
      bh[c] = *(const f16x8*)(Whi + col * 256 + k0 + koff);
      bl[c] = *(const f16x8*)(Wlo + col * 256 + k0 + koff);
    }
    #pragma unroll
    for (int r = 0; r < 4; r++) {
      int row = row_base + r * 16 + l16;
      if (row >= N) row = N - 1;
      f16x8 a = *(const f16x8*)(Abase + (size_t)row * 32 + koff);
      #pragma unroll
      for (int c = 0; c < 2; c++) {
        acc[r][c] = __builtin_amdgcn_mfma_f32_16x16x32_f16(a, bh[c], acc[r][c], 0, 0, 0);
        acc[r][c] = __builtin_amdgcn_mfma_f32_16x16x32_f16(a, bl[c], acc[r][c], 0, 0, 0);
      }
    }
  }

  #pragma unroll
  for (int r = 0; r < 4; r++) {
    #pragma unroll
    for (int c = 0; c < 2; c++) {
      int cc = col_base + c * 16 + l16;
      float b = bias[cc] * bscale;
      #pragma unroll
      for (int tt = 0; tt < 4; tt++) {
        int row = row_base + r * 16 + khalf * 4 + tt;
        if (row < N) {
          float v = acc[r][c][tt] + b;
          outp[(size_t)wv * planeN + (size_t)row * 32 + (c * 16 + l16)] =
              (_Float16)(v > 0.f ? v : 0.f);
        }
      }
    }
  }
}

// ---------------- fused pool + MLP head (batch sorted, plane reads) ----------------
static __device__ __forceinline__ int lbound(const int* __restrict__ a, int n, int v) {
  int lo = 0, hi = n;
  while (lo < hi) {
    int m = (lo + hi) >> 1;
    if (a[m] < v) lo = m + 1; else hi = m;
  }
  return lo;
}

__global__ __launch_bounds__(128) void poolhead_kernel(const _Float16* __restrict__ h,
                                                       const int* __restrict__ batch,
                                                       const float* __restrict__ fc1W,
                                                       const float* __restrict__ fc1b,
                                                       const float* __restrict__ fc2W,
                                                       const float* __restrict__ fc2b,
                                                       float* __restrict__ out, int N,
                                                       float unscale) {
  int gid = blockIdx.x, j = threadIdx.x;
  int start = lbound(batch, N, gid);
  int end = lbound(batch, N, gid + 1);
  size_t planeN = (size_t)N * 32;
  const _Float16* __restrict__ base = h + (size_t)(j >> 5) * planeN + (j & 31);
  float acc = 0.f;
  int r = start;
  for (; r + 3 < end; r += 4) {
    acc += (float)base[(size_t)r * 32] + (float)base[(size_t)(r + 1) * 32] +
           (float)base[(size_t)(r + 2) * 32] + (float)base[(size_t)(r + 3) * 32];
  }
  for (; r < end; ++r) acc += (float)base[(size_t)r * 32];
  __shared__ float grow[128];
  __shared__ float red[128];
  grow[j] = acc * unscale;
  __syncthreads();
  float a1 = fc1b[j];
  #pragma unroll 8
  for (int k = 0; k < 128; ++k) a1 = fmaf(grow[k], fc1W[k * 128 + j], a1);
  a1 = a1 > 0.f ? a1 : 0.f;
  red[j] = a1 * fc2W[j];
  __syncthreads();
  #pragma unroll
  for (int s2 = 64; s2 > 0; s2 >>= 1) {
    if (j < s2) red[j] += red[j + s2];
    __syncthreads();
  }
  if (j == 0) out[gid] = red[0] + fc2b[0];
}

extern "C" void kernel_launch(void* const* d_in, const int* in_sizes, int n_in,
                              void* d_out, int out_size, void* d_ws, size_t ws_size,
                              hipStream_t stream) {
  const float* x = (const float*)d_in[0];
  const int* edge = (const int*)d_in[1];
  const int* batch = (const int*)d_in[2];
  const int N = in_sizes[0] / 128;
  const int E = in_sizes[1] / 2;
  const int G = out_size;
  const int* esrc = edge;
  const int* edst = edge + E;
  const int NB = (N + 127) >> BSH;  // buckets
  const int nb1 = (E + CHUNK - 1) / CHUNK;

  char* ws = (char*)d_ws;
  size_t off = 0;
  auto alloc = [&](size_t bytes) -> void* {
    void* p = ws + off;
    off = (off + bytes + 255) & ~(size_t)255;
    return p;
  };
  _Float16* x16  = (_Float16*)alloc((size_t)N * 128 * 2);
  _Float16* bufA = (_Float16*)alloc((size_t)N * 128 * 2);
  _Float16* bufB = (_Float16*)alloc((size_t)N * 128 * 2);
  _Float16* agg  = (_Float16*)alloc((size_t)N * 128 * 2);
  _Float16* Whi  = (_Float16*)alloc((size_t)5 * 32768 * 2);
  _Float16* Wlo  = (_Float16*)alloc((size_t)5 * 32768 * 2);
  int* row_ptr   = (int*)alloc((size_t)(N + 1) * 4);
  int* col       = (int*)alloc((size_t)E * 4);
  int2* pairs    = (int2*)alloc((size_t)E * 8);
  int* blkhist   = (int*)alloc((size_t)nb1 * 512 * 4);
  int* base      = (int*)alloc(520 * 4);
  int* gcursor   = (int*)alloc(512 * 4);
  if (off > ws_size) return;  // fail loudly

  bhist_kernel<<<nb1, 256, 0, stream>>>(edst, blkhist, E, NB);
  bscan_kernel<<<1, 512, 0, stream>>>(blkhist, nb1, base, gcursor, NB, E);
  bscatter_kernel<<<nb1, 256, 0, stream>>>(esrc, edst, gcursor, pairs, E, NB);
  bbuild_kernel<<<NB, 256, 0, stream>>>(pairs, base, row_ptr, col, N, E);

  cvt_kernel<<<(N * 32 + 255) / 256, 256, 0, stream>>>(x, x16, N);

  // h'_l = h_l / 8^l keeps fp16 in range; weights *1/8, bias *8^-(l+1), undone at pool.
  const float S = 8.0f;
  W10 wp;
  for (int l = 0; l < 5; ++l) {
    wp.p[l] = (const float*)d_in[4 + 3 * l];
    wp.p[5 + l] = (const float*)d_in[6 + 3 * l];
  }
  prep_kernel<<<640, 256, 0, stream>>>(wp, Whi, Wlo, 1.0f / S);

  const _Float16* hin = x16;
  _Float16* hout = bufA;
  int nbpp = (N + 63) / 64;           // blocks per pass
  int gemm_grid = (N + 63) / 64;
  float bscale = 1.0f;
  for (int l = 0; l < 5; ++l) {
    bscale /= S;
    spmm_kernel<<<4 * nbpp, 256, 0, stream>>>(hin, row_ptr, col, agg, N, nbpp);
    gemm_kernel<<<gemm_grid, 256, 0, stream>>>(agg, hin,
                                               Whi + (size_t)l * 32768, Wlo + (size_t)l * 32768,
                                               (const float*)d_in[5 + 3 * l], bscale, hout, N);
    hin = hout;
    hout = (hout == bufA) ? bufB : bufA;
  }
  poolhead_kernel<<<G, 128, 0, stream>>>(hin, batch,
                                         (const float*)d_in[19], (const float*)d_in[20],
                                         (const float*)d_in[21], (const float*)d_in[22],
                                         (float*)d_out, N, 32768.0f);
}

// Round 13
// 371.981 us; speedup vs baseline: 1.8119x; 1.0525x over previous
//
#include <hip/hip_runtime.h>
#include <hip/hip_bf16.h>

typedef __attribute__((ext_vector_type(4))) float f32x4;
typedef __attribute__((ext_vector_type(8))) _Float16 f16x8;
typedef __attribute__((ext_vector_type(4))) _Float16 f16x4;

#define CHUNK 4096   // edges per pass-1 block
#define BSH 7        // nodes per bucket = 128
#define CAP 4096     // max edges per bucket handled in LDS fast path

// h layout: 4 feature-quarter planes, plane p holds columns [32p,32p+32) of all
// rows contiguously: hp[p*N*32 + r*32 + c]. A plane (3.2 MB) fits each XCD L2.

// ---------------- fp32 -> fp16 convert into planes ----------------
__global__ __launch_bounds__(256) void cvt_kernel(const float* __restrict__ x,
                                                  _Float16* __restrict__ hp, int N) {
  int i = blockIdx.x * blockDim.x + threadIdx.x;  // over N*32 quads of 4 elems
  if (i < N * 32) {
    int r = i >> 5, jg = i & 31;
    float4 v = *(const float4*)(x + (size_t)r * 128 + jg * 4);
    f16x4 o = {(_Float16)v.x, (_Float16)v.y, (_Float16)v.z, (_Float16)v.w};
    int plane = jg >> 3, wc = (jg & 7) * 4;
    *(f16x4*)(hp + (size_t)plane * N * 32 + (size_t)r * 32 + wc) = o;
  }
}

// ---------------- CSR build: bucketed counting sort ----------------
__global__ __launch_bounds__(256) void bhist_kernel(const int* __restrict__ dst,
                                                    int* __restrict__ blkhist, int E, int nb) {
  __shared__ int l[512];
  int t = threadIdx.x;
  for (int i = t; i < 512; i += 256) l[i] = 0;
  __syncthreads();
  int cbase = blockIdx.x * CHUNK;
  #pragma unroll
  for (int i = 0; i < CHUNK / 256; ++i) {
    int idx = cbase + i * 256 + t;
    if (idx < E) atomicAdd(&l[dst[idx] >> BSH], 1);
  }
  __syncthreads();
  for (int i = t; i < 512; i += 256) blkhist[blockIdx.x * 512 + i] = l[i];
}

__global__ __launch_bounds__(512) void bscan_kernel(const int* __restrict__ blkhist, int nblk,
                                                    int* __restrict__ base,
                                                    int* __restrict__ gcursor, int nb, int E) {
  __shared__ int wsum[8], wpre[8];
  int t = threadIdx.x, lane = t & 63, w = t >> 6;
  int v = 0;
  int b = 0;
  for (; b + 4 <= nblk; b += 4)
    v += blkhist[b * 512 + t] + blkhist[(b + 1) * 512 + t] +
         blkhist[(b + 2) * 512 + t] + blkhist[(b + 3) * 512 + t];
  for (; b < nblk; ++b) v += blkhist[b * 512 + t];
  int incl = v;
  #pragma unroll
  for (int o = 1; o < 64; o <<= 1) {
    int x = __shfl_up(incl, o, 64);
    if (lane >= o) incl += x;
  }
  if (lane == 63) wsum[w] = incl;
  __syncthreads();
  if (t == 0) {
    int run = 0;
    #pragma unroll
    for (int q = 0; q < 8; ++q) { wpre[q] = run; run += wsum[q]; }
  }
  __syncthreads();
  int excl = wpre[w] + incl - v;
  if (t < nb) { base[t] = excl; gcursor[t] = excl; }
  if (t == 0) base[nb] = E;
}

__global__ __launch_bounds__(256) void bscatter_kernel(const int* __restrict__ src,
                                                       const int* __restrict__ dst,
                                                       int* __restrict__ gcursor,
                                                       int2* __restrict__ pairs, int E, int nb) {
  __shared__ int lcnt[512], lstart[512], lpos[512], lgbase[512];
  __shared__ int2 lp[CHUNK];
  __shared__ int wsum[4], wpre[4];
  int t = threadIdx.x, lane = t & 63, w = t >> 6;
  for (int i = t; i < 512; i += 256) lcnt[i] = 0;
  __syncthreads();
  int cbase = blockIdx.x * CHUNK;
  int m = E - cbase; if (m > CHUNK) m = CHUNK;
  #pragma unroll
  for (int i = 0; i < CHUNK / 256; ++i) {
    int idx = i * 256 + t;
    if (idx < m) atomicAdd(&lcnt[dst[cbase + idx] >> BSH], 1);
  }
  __syncthreads();
  int c0 = lcnt[2 * t], c1 = lcnt[2 * t + 1];
  int s = c0 + c1, incl = s;
  #pragma unroll
  for (int o = 1; o < 64; o <<= 1) {
    int x = __shfl_up(incl, o, 64);
    if (lane >= o) incl += x;
  }
  if (lane == 63) wsum[w] = incl;
  __syncthreads();
  if (t == 0) {
    int run = 0;
    #pragma unroll
    for (int q = 0; q < 4; ++q) { wpre[q] = run; run += wsum[q]; }
  }
  __syncthreads();
  int excl = wpre[w] + incl - s;
  lstart[2 * t] = excl;          lpos[2 * t] = excl;
  lstart[2 * t + 1] = excl + c0; lpos[2 * t + 1] = excl + c0;
  if (2 * t < nb && c0 > 0) lgbase[2 * t] = atomicAdd(&gcursor[2 * t], c0);
  if (2 * t + 1 < nb && c1 > 0) lgbase[2 * t + 1] = atomicAdd(&gcursor[2 * t + 1], c1);
  __syncthreads();
  #pragma unroll
  for (int i = 0; i < CHUNK / 256; ++i) {
    int idx = i * 256 + t;
    if (idx < m) {
      int d = dst[cbase + idx], sv = src[cbase + idx];
      int p = atomicAdd(&lpos[d >> BSH], 1);
      lp[p] = make_int2(sv, d);
    }
  }
  __syncthreads();
  for (int i = t; i < m; i += 256) {
    int2 pr = lp[i];
    int b = pr.y >> BSH;
    pairs[lgbase[b] + (i - lstart[b])] = pr;
  }
}

__global__ __launch_bounds__(256) void bbuild_kernel(const int2* __restrict__ pairs,
                                                     const int* __restrict__ base,
                                                     int* __restrict__ row_ptr,
                                                     int* __restrict__ col, int N, int E) {
  __shared__ int cnt[128], cur[128], w2[2];
  __shared__ int cl[CAP];
  int b = blockIdx.x, t = threadIdx.x;
  int mb = base[b], me = base[b + 1], m = me - mb;
  if (t < 128) cnt[t] = 0;
  __syncthreads();
  for (int i = t; i < m; i += 256) atomicAdd(&cnt[pairs[mb + i].y & 127], 1);
  __syncthreads();
  int v = 0, incl = 0;
  if (t < 128) {
    v = cnt[t]; incl = v;
    #pragma unroll
    for (int o = 1; o < 64; o <<= 1) {
      int x = __shfl_up(incl, o, 64);
      if ((t & 63) >= o) incl += x;
    }
    if ((t & 63) == 63) w2[t >> 6] = incl;
  }
  __syncthreads();
  if (t < 128) {
    int excl = incl - v + ((t & 64) ? w2[0] : 0);
    cur[t] = excl;
    int node = (b << BSH) + t;
    if (node < N) row_ptr[node] = mb + excl;
  }
  if (b == 0 && t == 0) row_ptr[N] = E;
  __syncthreads();
  if (m <= CAP) {
    for (int i = t; i < m; i += 256) {
      int2 p = pairs[mb + i];
      int pos = atomicAdd(&cur[p.y & 127], 1);
      cl[pos] = p.x;
    }
    __syncthreads();
    for (int i = t; i < m; i += 256) col[mb + i] = cl[i];
  } else {
    for (int i = t; i < m; i += 256) {
      int2 p = pairs[mb + i];
      int pos = atomicAdd(&cur[p.y & 127], 1);
      col[mb + pos] = p.x;
    }
  }
}

// ---------------- weight prep: all 5 layers in one launch ----------------
struct W10 { const float* p[10]; };  // p[0..4]=Wrel, p[5..9]=Wroot

__global__ __launch_bounds__(256) void prep_kernel(W10 wp, _Float16* __restrict__ Whi,
                                                   _Float16* __restrict__ Wlo, float wscale) {
  int l = blockIdx.x >> 7;
  int idx = (blockIdx.x & 127) * 256 + threadIdx.x;  // col*256 + k
  int col = idx >> 8;
  int k = idx & 255;
  const float* __restrict__ Wrel = wp.p[l];
  const float* __restrict__ Wroot = wp.p[5 + l];
  float v = (k < 128) ? Wrel[k * 128 + col] : Wroot[(k - 128) * 128 + col];
  v *= wscale;
  _Float16 hi = (_Float16)v;
  _Float16 lo = (_Float16)(v - (float)hi);
  Whi[(size_t)l * 32768 + idx] = hi;
  Wlo[(size_t)l * 32768 + idx] = lo;
}

// ---------------- SpMM over feature-quarter planes ----------------
// pass p: gather 64B/edge from plane p (3.2 MB, L2-resident per XCD).
// 4-lane quads own one dst row; 8-deep col-prefetched pipeline.
__global__ __launch_bounds__(256) void spmm_kernel(const _Float16* __restrict__ hplanes,
                                                   const int* __restrict__ row_ptr,
                                                   const int* __restrict__ col,
                                                   _Float16* __restrict__ aggplanes,
                                                   int N, int nbpp) {
  int pass = blockIdx.x / nbpp;
  int blk = blockIdx.x - pass * nbpp;
  int t = threadIdx.x;
  int quad = t >> 2, lq = t & 3;
  int row = blk * 64 + quad;
  if (row >= N) return;
  size_t planeN = (size_t)N * 32;
  const char* __restrict__ hb = (const char*)(hplanes + (size_t)pass * planeN);
  unsigned lofs = (unsigned)lq << 4;
  int s = row_ptr[row], e = row_ptr[row + 1];
  float acc[8];
  #pragma unroll
  for (int q = 0; q < 8; ++q) acc[q] = 0.f;
  if (s < e) {
    int c[8];
    #pragma unroll
    for (int q = 0; q < 8; ++q) { int x = s + q; c[q] = col[x < e ? x : e - 1]; }
    int i = s;
    for (; i + 8 <= e; i += 8) {
      f16x8 v[8];
      #pragma unroll
      for (int q = 0; q < 8; ++q) v[q] = *(const f16x8*)(hb + ((((unsigned)c[q]) << 6) | lofs));
      #pragma unroll
      for (int q = 0; q < 8; ++q) { int x = i + 8 + q; c[q] = col[x < e ? x : e - 1]; }
      #pragma unroll
      for (int z = 0; z < 8; ++z)
        acc[z] += (((float)v[0][z] + (float)v[1][z]) + ((float)v[2][z] + (float)v[3][z])) +
                  (((float)v[4][z] + (float)v[5][z]) + ((float)v[6][z] + (float)v[7][z]));
    }
    if (i < e) {  // masked tail, c[] holds clamped indices
      f16x8 v[8];
      #pragma unroll
      for (int q = 0; q < 8; ++q) v[q] = *(const f16x8*)(hb + ((((unsigned)c[q]) << 6) | lofs));
      #pragma unroll
      for (int q = 0; q < 8; ++q) {
        float m = (i + q < e) ? 1.f : 0.f;
        #pragma unroll
        for (int z = 0; z < 8; ++z) acc[z] = fmaf(m, (float)v[q][z], acc[z]);
      }
    }
  }
  f16x8 o;
  #pragma unroll
  for (int q = 0; q < 8; ++q) o[q] = (_Float16)acc[q];
  *(f16x8*)(aggplanes + (size_t)pass * planeN + (size_t)row * 32 + lq * 8) = o;
}

// ---------------- dense GEMM over planes: out = relu(concat[agg,h] @ Wcat + b*bscale) ----------------
__global__ __launch_bounds__(256) void gemm_kernel(const _Float16* __restrict__ aggp,
                                                   const _Float16* __restrict__ hp,
                                                   const _Float16* __restrict__ Whi,
                                                   const _Float16* __restrict__ Wlo,
                                                   const float* __restrict__ bias,
                                                   float bscale,
                                                   _Float16* __restrict__ outp, int N) {
  size_t planeN = (size_t)N * 32;
  int wv = threadIdx.x >> 6;
  int lane = threadIdx.x & 63;
  int l16 = lane & 15;
  int khalf = lane >> 4;  // 0..3
  int koff = khalf * 8;
  int row_base = blockIdx.x * 64;
  int col_base = wv * 32;

  f32x4 acc[4][2];
  #pragma unroll
  for (int r = 0; r < 4; r++)
    #pragma unroll
    for (int c = 0; c < 2; c++) acc[r][c] = (f32x4){0.f, 0.f, 0.f, 0.f};

  #pragma unroll
  for (int ks = 0; ks < 8; ++ks) {
    int k0 = ks * 32;
    const _Float16* Abase = (ks < 4) ? (aggp + (size_t)ks * planeN)
                                     : (hp + (size_t)(ks - 4) * planeN);
    f16x8 bh[2], bl[2];
    #pragma unroll
    for (int c = 0; c < 2; c++) {
      int col = col_base + c * 16 + l16;
      bh[c] = *(const f16x8*)(Whi + col * 256 + k0 + koff);
      bl[c] = *(const f16x8*)(Wlo + col * 256 + k0 + koff);
    }
    #pragma unroll
    for (int r = 0; r < 4; r++) {
      int row = row_base + r * 16 + l16;
      if (row >= N) row = N - 1;
      f16x8 a = *(const f16x8*)(Abase + (size_t)row * 32 + koff);
      #pragma unroll
      for (int c = 0; c < 2; c++) {
        acc[r][c] = __builtin_amdgcn_mfma_f32_16x16x32_f16(a, bh[c], acc[r][c], 0, 0, 0);
        acc[r][c] = __builtin_amdgcn_mfma_f32_16x16x32_f16(a, bl[c], acc[r][c], 0, 0, 0);
      }
    }
  }

  #pragma unroll
  for (int r = 0; r < 4; r++) {
    #pragma unroll
    for (int c = 0; c < 2; c++) {
      int cc = col_base + c * 16 + l16;
      float b = bias[cc] * bscale;
      #pragma unroll
      for (int tt = 0; tt < 4; tt++) {
        int row = row_base + r * 16 + khalf * 4 + tt;
        if (row < N) {
          float v = acc[r][c][tt] + b;
          outp[(size_t)wv * planeN + (size_t)row * 32 + (c * 16 + l16)] =
              (_Float16)(v > 0.f ? v : 0.f);
        }
      }
    }
  }
}

// ---------------- fused pool + MLP head (batch sorted, plane reads) ----------------
static __device__ __forceinline__ int lbound(const int* __restrict__ a, int n, int v) {
  int lo = 0, hi = n;
  while (lo < hi) {
    int m = (lo + hi) >> 1;
    if (a[m] < v) lo = m + 1; else hi = m;
  }
  return lo;
}

__global__ __launch_bounds__(128) void poolhead_kernel(const _Float16* __restrict__ h,
                                                       const int* __restrict__ batch,
                                                       const float* __restrict__ fc1W,
                                                       const float* __restrict__ fc1b,
                                                       const float* __restrict__ fc2W,
                                                       const float* __restrict__ fc2b,
                                                       float* __restrict__ out, int N,
                                                       float unscale) {
  int gid = blockIdx.x, j = threadIdx.x;
  int start = lbound(batch, N, gid);
  int end = lbound(batch, N, gid + 1);
  size_t planeN = (size_t)N * 32;
  const _Float16* __restrict__ base = h + (size_t)(j >> 5) * planeN + (j & 31);
  float acc = 0.f;
  int r = start;
  for (; r + 3 < end; r += 4) {
    acc += (float)base[(size_t)r * 32] + (float)base[(size_t)(r + 1) * 32] +
           (float)base[(size_t)(r + 2) * 32] + (float)base[(size_t)(r + 3) * 32];
  }
  for (; r < end; ++r) acc += (float)base[(size_t)r * 32];
  __shared__ float grow[128];
  __shared__ float red[128];
  grow[j] = acc * unscale;
  __syncthreads();
  float a1 = fc1b[j];
  #pragma unroll 8
  for (int k = 0; k < 128; ++k) a1 = fmaf(grow[k], fc1W[k * 128 + j], a1);
  a1 = a1 > 0.f ? a1 : 0.f;
  red[j] = a1 * fc2W[j];
  __syncthreads();
  #pragma unroll
  for (int s2 = 64; s2 > 0; s2 >>= 1) {
    if (j < s2) red[j] += red[j + s2];
    __syncthreads();
  }
  if (j == 0) out[gid] = red[0] + fc2b[0];
}

extern "C" void kernel_launch(void* const* d_in, const int* in_sizes, int n_in,
                              void* d_out, int out_size, void* d_ws, size_t ws_size,
                              hipStream_t stream) {
  const float* x = (const float*)d_in[0];
  const int* edge = (const int*)d_in[1];
  const int* batch = (const int*)d_in[2];
  const int N = in_sizes[0] / 128;
  const int E = in_sizes[1] / 2;
  const int G = out_size;
  const int* esrc = edge;
  const int* edst = edge + E;
  const int NB = (N + 127) >> BSH;  // buckets
  const int nb1 = (E + CHUNK - 1) / CHUNK;

  char* ws = (char*)d_ws;
  size_t off = 0;
  auto alloc = [&](size_t bytes) -> void* {
    void* p = ws + off;
    off = (off + bytes + 255) & ~(size_t)255;
    return p;
  };
  _Float16* x16  = (_Float16*)alloc((size_t)N * 128 * 2);
  _Float16* bufA = (_Float16*)alloc((size_t)N * 128 * 2);
  _Float16* bufB = (_Float16*)alloc((size_t)N * 128 * 2);
  _Float16* agg  = (_Float16*)alloc((size_t)N * 128 * 2);
  _Float16* Whi  = (_Float16*)alloc((size_t)5 * 32768 * 2);
  _Float16* Wlo  = (_Float16*)alloc((size_t)5 * 32768 * 2);
  int* row_ptr   = (int*)alloc((size_t)(N + 1) * 4);
  int* col       = (int*)alloc((size_t)E * 4);
  int2* pairs    = (int2*)alloc((size_t)E * 8);
  int* blkhist   = (int*)alloc((size_t)nb1 * 512 * 4);
  int* base      = (int*)alloc(520 * 4);
  int* gcursor   = (int*)alloc(512 * 4);
  if (off > ws_size) return;  // fail loudly

  bhist_kernel<<<nb1, 256, 0, stream>>>(edst, blkhist, E, NB);
  bscan_kernel<<<1, 512, 0, stream>>>(blkhist, nb1, base, gcursor, NB, E);
  bscatter_kernel<<<nb1, 256, 0, stream>>>(esrc, edst, gcursor, pairs, E, NB);
  bbuild_kernel<<<NB, 256, 0, stream>>>(pairs, base, row_ptr, col, N, E);

  cvt_kernel<<<(N * 32 + 255) / 256, 256, 0, stream>>>(x, x16, N);

  // h'_l = h_l / 8^l keeps fp16 in range; weights *1/8, bias *8^-(l+1), undone at pool.
  const float S = 8.0f;
  W10 wp;
  for (int l = 0; l < 5; ++l) {
    wp.p[l] = (const float*)d_in[4 + 3 * l];
    wp.p[5 + l] = (const float*)d_in[6 + 3 * l];
  }
  prep_kernel<<<640, 256, 0, stream>>>(wp, Whi, Wlo, 1.0f / S);

  const _Float16* hin = x16;
  _Float16* hout = bufA;
  int nbpp = (N + 63) / 64;           // blocks per pass
  int gemm_grid = (N + 63) / 64;
  float bscale = 1.0f;
  for (int l = 0; l < 5; ++l) {
    bscale /= S;
    spmm_kernel<<<4 * nbpp, 256, 0, stream>>>(hin, row_ptr, col, agg, N, nbpp);
    gemm_kernel<<<gemm_grid, 256, 0, stream>>>(agg, hin,
                                               Whi + (size_t)l * 32768, Wlo + (size_t)l * 32768,
                                               (const float*)d_in[5 + 3 * l], bscale, hout, N);
    hin = hout;
    hout = (hout == bufA) ? bufB : bufA;
  }
  poolhead_kernel<<<G, 128, 0, stream>>>(hin, batch,
                                         (const float*)d_in[19], (const float*)d_in[20],
                                         (const float*)d_in[21], (const float*)d_in[22],
                                         (float*)d_out, N, 32768.0f);
}